// Round 1
// baseline (76.325 us; speedup 1.0000x reference)
//
#include <hip/hip_runtime.h>
#include <hip/hip_bf16.h>
#include <math.h>

// Temporal attention: B=32, N=2048, F=16, T=64
//   y[b,t,f]   = sum_n U1[n] * x[b,n,f,t]
//   rhs[b,n,u] = sum_f U3[f] * x[b,n,f,u]
//   z[b,f,u]   = sum_n U2[f,n] * rhs[b,n,u]
//   product[b,t,u] = sum_f y[b,t,f] * z[b,f,u]          (== lhs @ rhs)
//   E[b,t,u] = sum_s Ve[t,s] * sigmoid(product[b,s,u] + be[s,u])
//   out = softmax over t (axis=1)

#define B_ 32
#define N_ 2048
#define F_ 16
#define T_ 64
#define NPB 128              // n-rows per block in pass 1
#define CHUNKS (N_ / NPB)    // 16 chunks per batch

// ---------------- Pass 1: stream x once, emit per-(b,chunk) partial y/z ----
__global__ __launch_bounds__(256) void ta_pass1(
    const float* __restrict__ x, const float* __restrict__ U1,
    const float* __restrict__ U2, const float* __restrict__ U3,
    float* __restrict__ partial)
{
  const int blk    = blockIdx.x;
  const int b      = blk / CHUNKS;
  const int chunk  = blk % CHUNKS;
  const int n_base = chunk * NPB;
  const int tid    = threadIdx.x;
  const int tp     = tid & 31;   // t-pair index: covers t = 2*tp, 2*tp+1
  const int n_sub  = tid >> 5;   // 8 concurrent n per iteration

  __shared__ float u1s[NPB];
  __shared__ float u2s[F_][NPB];
  __shared__ float red[4 * 2048];   // per-wave partials for block reduction

  for (int i = tid; i < NPB; i += 256) u1s[i] = U1[n_base + i];
  for (int i = tid; i < F_ * NPB; i += 256) {
    int f = i / NPB, nl = i % NPB;
    u2s[f][nl] = U2[f * N_ + n_base + nl];
  }
  float u3r[F_];
  #pragma unroll
  for (int f = 0; f < F_; ++f) u3r[f] = U3[f];
  __syncthreads();

  float2 ya[F_], za[F_];
  #pragma unroll
  for (int f = 0; f < F_; ++f) {
    ya[f] = make_float2(0.f, 0.f);
    za[f] = make_float2(0.f, 0.f);
  }

  const float* xb = x + ((size_t)b * N_ + n_base) * (F_ * T_);
  for (int it = 0; it < NPB / 8; ++it) {
    const int nl = n_sub + it * 8;
    const float* xn = xb + (size_t)nl * (F_ * T_) + 2 * tp;
    const float u1 = u1s[nl];
    float r0 = 0.f, r1 = 0.f;
    #pragma unroll
    for (int f = 0; f < F_; ++f) {
      float2 v = *reinterpret_cast<const float2*>(xn + f * T_);
      ya[f].x = fmaf(u1, v.x, ya[f].x);
      ya[f].y = fmaf(u1, v.y, ya[f].y);
      r0 = fmaf(u3r[f], v.x, r0);
      r1 = fmaf(u3r[f], v.y, r1);
    }
    #pragma unroll
    for (int f = 0; f < F_; ++f) {
      const float u2 = u2s[f][nl];
      za[f].x = fmaf(u2, r0, za[f].x);
      za[f].y = fmaf(u2, r1, za[f].y);
    }
  }

  // Phase A: combine the two n_sub groups within each wave (lane <-> lane+32)
  #pragma unroll
  for (int f = 0; f < F_; ++f) {
    ya[f].x += __shfl_xor(ya[f].x, 32);
    ya[f].y += __shfl_xor(ya[f].y, 32);
    za[f].x += __shfl_xor(za[f].x, 32);
    za[f].y += __shfl_xor(za[f].y, 32);
  }
  // Phase B: per-wave partials to LDS, then sum the 4 waves
  const int lane = tid & 63, w = tid >> 6;
  if (lane < 32) {
    #pragma unroll
    for (int f = 0; f < F_; ++f) {
      red[w * 2048 + (f * 2 + 0) * 32 + tp]        = ya[f].x;  // y[t=2tp+0][f]
      red[w * 2048 + (f * 2 + 1) * 32 + tp]        = ya[f].y;  // y[t=2tp+1][f]
      red[w * 2048 + (32 + f * 2 + 0) * 32 + tp]   = za[f].x;  // z[f][u=2tp+0]
      red[w * 2048 + (32 + f * 2 + 1) * 32 + tp]   = za[f].y;  // z[f][u=2tp+1]
    }
  }
  __syncthreads();
  float* pb = partial + (size_t)blk * 2048;
  #pragma unroll
  for (int k = 0; k < 8; ++k) {
    int idx = tid + k * 256;
    pb[idx] = red[idx] + red[2048 + idx] + red[4096 + idx] + red[6144 + idx];
  }
}

// ---------------- Pass 2: reduce partials, product+sigmoid, Ve, softmax ----
__global__ __launch_bounds__(256) void ta_finish(
    const float* __restrict__ partial, const float* __restrict__ be,
    const float* __restrict__ Ve, float* __restrict__ out)
{
  const int b = blockIdx.x;
  const int tid = threadIdx.x;
  __shared__ float ys[T_][F_ + 1];
  __shared__ float zs[F_][T_ + 1];
  __shared__ float sig[T_][T_ + 1];
  __shared__ float Es[T_][T_ + 1];

  // reduce the CHUNKS per-block partials for this batch
  #pragma unroll
  for (int k = 0; k < 8; ++k) {
    const int idx = tid + k * 256;
    float s = 0.f;
    for (int j = 0; j < CHUNKS; ++j)
      s += partial[((size_t)b * CHUNKS + j) * 2048 + idx];
    const int vi = idx >> 5, tp = idx & 31;
    if (vi < 32) { int f = vi >> 1, c = vi & 1; ys[2 * tp + c][f] = s; }
    else { int v2 = vi - 32; int f = v2 >> 1, c = v2 & 1; zs[f][2 * tp + c] = s; }
  }
  __syncthreads();

  const int t  = tid >> 2;          // row 0..63
  const int ub = (tid & 3) * 16;    // 16-wide u slab
  #pragma unroll
  for (int i = 0; i < 16; ++i) {
    const int u = ub + i;
    float acc = 0.f;
    #pragma unroll
    for (int f = 0; f < F_; ++f) acc = fmaf(ys[t][f], zs[f][u], acc);
    acc += be[t * T_ + u];
    sig[t][u] = 1.f / (1.f + __expf(-acc));
  }
  __syncthreads();
  #pragma unroll
  for (int i = 0; i < 16; ++i) {
    const int u = ub + i;
    float acc = 0.f;
    #pragma unroll
    for (int s = 0; s < T_; ++s) acc = fmaf(Ve[t * T_ + s], sig[s][u], acc);
    Es[t][u] = acc;
  }
  __syncthreads();

  // softmax over t (axis=1), one thread per column u
  if (tid < T_) {
    const int u = tid;
    float m = -INFINITY;
    for (int t2 = 0; t2 < T_; ++t2) m = fmaxf(m, Es[t2][u]);
    float den = 0.f;
    for (int t2 = 0; t2 < T_; ++t2) den += __expf(Es[t2][u] - m);
    const float inv = 1.f / den;
    for (int t2 = 0; t2 < T_; ++t2)
      out[(size_t)b * T_ * T_ + t2 * T_ + u] = __expf(Es[t2][u] - m) * inv;
  }
}

extern "C" void kernel_launch(void* const* d_in, const int* in_sizes, int n_in,
                              void* d_out, int out_size, void* d_ws, size_t ws_size,
                              hipStream_t stream) {
  const float* x  = (const float*)d_in[0];
  const float* U1 = (const float*)d_in[1];
  const float* U2 = (const float*)d_in[2];
  const float* U3 = (const float*)d_in[3];
  const float* be = (const float*)d_in[4];
  const float* Ve = (const float*)d_in[5];
  float* out = (float*)d_out;
  float* partial = (float*)d_ws;   // needs B_*CHUNKS*2048*4 = 4 MB of scratch

  ta_pass1<<<B_ * CHUNKS, 256, 0, stream>>>(x, U1, U2, U3, partial);
  ta_finish<<<B_, 256, 0, stream>>>(partial, be, Ve, out);
}